// Round 16
// baseline (52.365 us; speedup 1.0000x reference)
//
#include <hip/hip_runtime.h>
#include <hip/hip_fp16.h>
#include <stdint.h>

// Problem constants (match reference)
#define BB 16384
#define SS 20
#define DD 128
#define EPSV 1e-5f

// R16 = R14 EXACT structure; single variable changed: all packed-f16
// arithmetic goes through HIP's canonical __half2 intrinsics
// (__hfma2/__hadd2 -> guaranteed v_pk_fma_f16/v_pk_add_f16) instead of
// hand-rolled ext_vector operators, which the R14 counter arithmetic
// suggests hipcc scalarized into 2x v_fma_f16 (implied 2712 inst/wave vs
// ~1400 hand-counted packed). One wave = 1 batch row; lane owns the d-pair
// (d0=2*lane, d0+1) packed as ONE f16x2 per s -> X[20] = 20 VGPR persistent.
// Conv: 4 bperm + 2 alignbit + 8 packed fma per t. Gate: 20 packed fma/t on
// broadcast-packed weights (wave-uniform s_load). Two-pass prologue (R11).
// NO launch_bounds min-waves arg (R6/R12/R13). Spill tripwire: FETCH >> 1.5MB.

#define BPERMU(addr, v) ((uint32_t)__builtin_amdgcn_ds_bpermute((addr), (int)(v)))

static __device__ __forceinline__ uint32_t pk16(float a, float b) {
    return __builtin_bit_cast(uint32_t, __builtin_amdgcn_cvt_pkrtz(a, b));
}
static __device__ __forceinline__ __half2 H2(uint32_t u) {
    return __builtin_bit_cast(__half2, u);
}

// ---- prep: broadcast-pack gate_w (400) + conv weights (20x8) into ws ----
// ws[0..399]          : gwb[t*20+s] = (w[t][s], w[t][s]) f16x2
// ws[400 + t*8 + 0..7]: {wc0, wb0, wa0, cw, wa2, wb2, wc2, bias} pairs
__global__ void pack_w_kernel(const float* __restrict__ gate_w,
                              const float* __restrict__ w0, const float* __restrict__ b0,
                              const float* __restrict__ w1, const float* __restrict__ b1,
                              const float* __restrict__ w2, const float* __restrict__ b2,
                              uint32_t*    __restrict__ ws) {
    const int i = threadIdx.x;             // single block of 512
    if (i < SS * SS) {
        const float v = gate_w[i];
        ws[i] = pk16(v, v);
    }
    if (i < SS) {
        const float wa0 = w0[i*3+0], wam = w0[i*3+1], wa2 = w0[i*3+2];
        const float wb0 = w1[i*3+0], wbm = w1[i*3+1], wb2 = w1[i*3+2];
        const float wc0 = w2[i*3+0], wcm = w2[i*3+1], wc2 = w2[i*3+2];
        const float cw   = wam + wbm + wcm;
        const float bias = b0[i] + b1[i] + b2[i];
        uint32_t* o = ws + SS * SS + i * 8;
        o[0] = pk16(wc0, wc0);  o[1] = pk16(wb0, wb0);
        o[2] = pk16(wa0, wa0);  o[3] = pk16(cw,  cw);
        o[4] = pk16(wa2, wa2);  o[5] = pk16(wb2, wb2);
        o[6] = pk16(wc2, wc2);  o[7] = pk16(bias, bias);
    }
}

__global__ __launch_bounds__(256) void fused_mdt_kernel(
    const int*      __restrict__ tokens,   // [B,S]
    const float*    __restrict__ emb,      // [V,D] (6 KB, cache-resident)
    const float*    __restrict__ pre_w,    // [S]
    const uint32_t* __restrict__ wpk,      // packed weights (from prep)
    const float*    __restrict__ gate_b,   // [S]
    const float*    __restrict__ post_w,   // [S]
    const float*    __restrict__ logit_w,  // [1,S,1] -> flat [S]
    float*          __restrict__ out)      // [B,1,D] -> flat [B*D]
{
    const int tid  = threadIdx.x;
    const int lane = tid & 63;             // one row per wave
    const int b    = __builtin_amdgcn_readfirstlane(blockIdx.x * 4 + (tid >> 6));
    const int d0   = lane << 1;

    // edge masks ('same' zero padding):
    //   L1 (lane-1): mL1 = lane==0   L2 (lane-2): mL2 = lane<2
    //   R1 (lane+1): mR1 = lane==63  R2 (lane+2): mR2 = lane>=62
    const bool mL1 = (lane == 0);
    const bool mL2 = (lane <  2);
    const bool mR1 = (lane == 63);
    const bool mR2 = (lane >= 62);
    const int aL2 = (lane - 2) << 2;
    const int aL1 = (lane - 1) << 2;
    const int aR1 = (lane + 1) << 2;
    const int aR2 = (lane + 2) << 2;

    const int* tb = tokens + b * SS;       // wave-uniform -> SGPR s_loads

    // ---- pass A: stream emb for RMS stats + residual dot; store nothing ----
    float ms0 = 0.f, ms1 = 0.f, a10 = 0.f, a11 = 0.f;
    #pragma unroll
    for (int s = 0; s < SS; ++s) {
        const float2 v = *reinterpret_cast<const float2*>(emb + tb[s] * DD + d0);
        ms0 = fmaf(v.x, v.x, ms0);
        ms1 = fmaf(v.y, v.y, ms1);
        const float lw = logit_w[s];
        a10 = fmaf(v.x, lw, a10);
        a11 = fmaf(v.y, lw, a11);
    }
    const float r0 = rsqrtf(ms0 * (1.f/SS) + EPSV);
    const float r1 = rsqrtf(ms1 * (1.f/SS) + EPSV);

    __builtin_amdgcn_sched_barrier(0);

    // ---- pass B: re-read emb (L1-hot), normalize, pack d-pairs ----
    uint32_t X[SS];
    #pragma unroll
    for (int s = 0; s < SS; ++s) {
        const float2 v = *reinterpret_cast<const float2*>(emb + tb[s] * DD + d0);
        const float pw = pre_w[s];
        X[s] = pk16(v.x * (r0 * pw), v.y * (r1 * pw));
    }

    __builtin_amdgcn_sched_barrier(0);

    // ---- main loop over t: 4 bperm + packed conv + packed gate + SiLU ----
    float m20 = 0.f, m21 = 0.f, ac0 = 0.f, ac1 = 0.f;
    #pragma unroll
    for (int t = 0; t < SS; ++t) {
        uint32_t L2u = BPERMU(aL2, X[t]);
        uint32_t L1u = BPERMU(aL1, X[t]);
        uint32_t R1u = BPERMU(aR1, X[t]);
        uint32_t R2u = BPERMU(aR2, X[t]);
        L2u = mL2 ? 0u : L2u;
        L1u = mL1 ? 0u : L1u;
        R1u = mR1 ? 0u : R1u;
        R2u = mR2 ? 0u : R2u;
        // lane-pair splices for the +-1 taps:
        //   Dm1 = (lo = L1.hi [d0-1], hi = own.lo [d0])
        //   Dp1 = (lo = own.hi [d0+1], hi = R1.lo [d0+2])
        const uint32_t Dm1 = __builtin_amdgcn_alignbit(X[t], L1u, 16);
        const uint32_t Dp1 = __builtin_amdgcn_alignbit(R1u, X[t], 16);

        // conv: 7 packed fma via __hfma2 (weights broadcast-packed, s_load)
        const uint32_t* cw8 = wpk + SS * SS + t * 8;
        __half2 xd = H2(cw8[7]);                      // bias pair
        xd = __hfma2(H2(cw8[0]), H2(L2u),  xd);       // d-4
        xd = __hfma2(H2(cw8[1]), H2(L1u),  xd);       // d-2
        xd = __hfma2(H2(cw8[2]), H2(Dm1),  xd);       // d-1
        xd = __hfma2(H2(cw8[3]), H2(X[t]), xd);       // center (merged)
        xd = __hfma2(H2(cw8[4]), H2(Dp1),  xd);       // d+1
        xd = __hfma2(H2(cw8[5]), H2(R1u),  xd);       // d+2
        xd = __hfma2(H2(cw8[6]), H2(R2u),  xd);       // d+4

        // gate row t: 20 packed fma (__hfma2), 2 split chains; bias in f32
        __half2 ga = H2(0u), gb = H2(0u);
        #pragma unroll
        for (int q = 0; q < SS / 2; ++q) {
            ga = __hfma2(H2(wpk[t * SS + 2*q    ]), H2(X[2*q    ]), ga);
            gb = __hfma2(H2(wpk[t * SS + 2*q + 1]), H2(X[2*q + 1]), gb);
        }
        const __half2 gp = __hadd2(ga, gb);
        const float gbv = gate_b[t];
        const float g0 = __low2float(gp)  + gbv;
        const float g1 = __high2float(gp) + gbv;
        const float xd0 = __low2float(xd);
        const float xd1 = __high2float(xd);

        // SiLU + post-RMS accumulation (f32)
        const float pl = post_w[t] * logit_w[t];
        const float h0 = xd0 * (g0 * __builtin_amdgcn_rcpf(1.f + __expf(-g0)));
        const float h1 = xd1 * (g1 * __builtin_amdgcn_rcpf(1.f + __expf(-g1)));
        m20 = fmaf(h0, h0, m20);
        m21 = fmaf(h1, h1, m21);
        ac0 = fmaf(h0, pl, ac0);
        ac1 = fmaf(h1, pl, ac1);
    }

    const float q0 = rsqrtf(m20 * (1.f/SS) + EPSV);
    const float q1 = rsqrtf(m21 * (1.f/SS) + EPSV);

    float2 res;
    res.x = a10 + q0 * ac0;
    res.y = a11 + q1 * ac1;
    *reinterpret_cast<float2*>(out + b * DD + d0) = res;
}

extern "C" void kernel_launch(void* const* d_in, const int* in_sizes, int n_in,
                              void* d_out, int out_size, void* d_ws, size_t ws_size,
                              hipStream_t stream) {
    const int*   tokens  = (const int*)  d_in[0];
    // d_in[1] = number_log — unused by the reference
    const float* emb     = (const float*)d_in[2];
    const float* pre_w   = (const float*)d_in[3];
    const float* w0      = (const float*)d_in[4];
    const float* b0      = (const float*)d_in[5];
    const float* w1      = (const float*)d_in[6];
    const float* b1      = (const float*)d_in[7];
    const float* w2      = (const float*)d_in[8];
    const float* b2      = (const float*)d_in[9];
    const float* gate_w  = (const float*)d_in[10];
    const float* gate_b  = (const float*)d_in[11];
    const float* post_w  = (const float*)d_in[12];
    const float* logit_w = (const float*)d_in[13];
    float*       out     = (float*)d_out;
    uint32_t*    ws      = (uint32_t*)d_ws;

    hipLaunchKernelGGL(pack_w_kernel, dim3(1), dim3(512), 0, stream,
                       gate_w, w0, b0, w1, b1, w2, b2, ws);

    dim3 grid(BB / 4);   // 4 rows (4 waves) per 256-thread block -> 4096 blocks
    dim3 block(256);
    hipLaunchKernelGGL(fused_mdt_kernel, grid, block, 0, stream,
                       tokens, emb, pre_w, (const uint32_t*)ws,
                       gate_b, post_w, logit_w, out);
}